// Round 11
// baseline (1803.406 us; speedup 1.0000x reference)
//
#include <hip/hip_runtime.h>

#define Rn 64
#define Hn 10
#define Fn 5
#define TT 4            // steps per tile
#define NTL (Rn / TT)   // 16 tiles

typedef float f32x2 __attribute__((ext_vector_type(2)));
typedef float f32x4 __attribute__((ext_vector_type(4)));

#define PKFMA(a, b, c) __builtin_elementwise_fma((a), (b), (c))

__device__ __forceinline__ float fsigmoid(float x) {
    return __builtin_amdgcn_rcpf(1.0f + __expf(-x));
}
__device__ __forceinline__ float ftanh(float x) {
    return 1.0f - 2.0f * __builtin_amdgcn_rcpf(__expf(2.0f * x) + 1.0f);
}
__device__ __forceinline__ float bperm(int addr, float v) {
    return __int_as_float(__builtin_amdgcn_ds_bpermute(addr, __float_as_int(v)));
}

// 4 lanes per batch, ROW-split (lane sub owns rows 3sub..3sub+2, 12-row pad):
// W_hh + Wh for own rows live in VGPRs (LDS-resident weights cost a fixed
// ~9k cy/step/CU of LDS return bandwidth -- broadcasts are NOT deduplicated,
// measured rounds 4/8/10). c-update and h_new are lane-local; only the
// h_{t+1} broadcast crosses lanes (10 ds_bpermute). The x-projection
// (recurrence-independent) runs in a per-4-step phase-A reading W_ih/Wr from
// a small LDS stack once per row and x straight from global/L1 (contiguous,
// no LDS staging); results + biases spill to per-lane LDS scratch. Pad rows
// produce zeros end-to-end (zero W, zero bias, zero Wfc slots).
__global__ __launch_bounds__(256, 2) void seqreader_kernel(
    const float* __restrict__ r_emb, const float* __restrict__ feature,
    const float* __restrict__ h0, const float* __restrict__ c0,
    const float* __restrict__ W_ih, const float* __restrict__ W_hh,
    const float* __restrict__ b_ih, const float* __restrict__ b_hh,
    const float* __restrict__ Wr, const float* __restrict__ br,
    const float* __restrict__ Wh, const float* __restrict__ bh,
    const float* __restrict__ Wfc, const float* __restrict__ bfc,
    float* __restrict__ out)
{
    // sWX: 60 row-slots x 12 dw. Slots 0..47: W_ih gate g row r at g*12+r
    // (rows 10,11 zero); 48..59: Wr row r. dw 0..9 = weights, dw10 = bias
    // (b_ih+b_hh or br+bh), dw11 = 0.
    __shared__ __align__(16) float sWX[60 * 12];
    __shared__ float sWfc[64 * 12];           // [t][12]: dw 0..9 real, 10..11 = 0
    __shared__ __align__(16) float sG[256 * 66];  // per-thread gx scratch

    const int tid  = threadIdx.x;
    const int lane = tid & 63;
    const int sub  = lane & 3;
    const int grp  = lane >> 2;
    const int b    = blockIdx.x * 64 + (tid >> 6) * 16 + grp;

    // ---- stage sWX / sWfc (zeros first, then scatter; one barrier pair) ----
    for (int i = tid; i < 720; i += 256) sWX[i] = 0.f;
    for (int i = tid; i < 768; i += 256) sWfc[i] = 0.f;
    __syncthreads();
    for (int i = tid; i < 400; i += 256) {
        int g = i / 100, r = (i / 10) % 10, k = i % 10;
        sWX[(g * 12 + r) * 12 + k] = W_ih[i];
    }
    for (int i = tid; i < 100; i += 256) {
        int r = i / 10, k = i % 10;
        sWX[(48 + r) * 12 + k] = Wr[i];
    }
    for (int i = tid; i < 40; i += 256) {
        int g = i / 10, r = i % 10;
        sWX[(g * 12 + r) * 12 + 10] = b_ih[i] + b_hh[i];
    }
    if (tid < 10) sWX[(48 + tid) * 12 + 10] = br[tid] + bh[tid];
    for (int i = tid; i < 640; i += 256) sWfc[(i / 10) * 12 + (i % 10)] = Wfc[i];

    // ---- VGPR-resident recurrent weights (own rows, guarded pads) ----
    f32x2 whh[4][3][5];   // [gate][own row j][k-pair]
    f32x2 wnh[3][5];      // Wh
    #pragma unroll
    for (int g = 0; g < 4; ++g)
        #pragma unroll
        for (int j = 0; j < 3; ++j) {
            const int r = 3 * sub + j;
            #pragma unroll
            for (int p = 0; p < 5; ++p)
                whh[g][j][p] = (r < 10) ? *(const f32x2*)&W_hh[(g * 10 + r) * 10 + 2 * p]
                                        : f32x2{0.f, 0.f};
        }
    #pragma unroll
    for (int j = 0; j < 3; ++j) {
        const int r = 3 * sub + j;
        #pragma unroll
        for (int p = 0; p < 5; ++p)
            wnh[j][p] = (r < 10) ? *(const f32x2*)&Wh[r * 10 + 2 * p] : f32x2{0.f, 0.f};
    }

    // state
    float c[3];
    #pragma unroll
    for (int j = 0; j < 3; ++j) {
        const int r = 3 * sub + j;
        c[j] = (r < 10) ? c0[(size_t)b * Hn + r] : 0.f;
    }
    f32x2 h2[5];
    #pragma unroll
    for (int p = 0; p < 5; ++p) h2[p] = *(const f32x2*)&h0[(size_t)b * Hn + 2 * p];

    float acc = 0.f;
    if (sub == 0) {
        acc = bfc[0];
        #pragma unroll
        for (int k = 0; k < Fn; ++k)
            acc = fmaf(feature[(size_t)b * Fn + k], Wfc[Rn * Hn + k], acc);
    }

    // bpermute source addresses: group base | owner sub
    const int gb4 = (lane & ~3) << 2;
    const int A0 = gb4, A1 = gb4 + 4, A2 = gb4 + 8, A3 = gb4 + 12;

    const float* __restrict__ xb = r_emb + (size_t)b * (Rn * Hn);
    const int gbase = tid * 66;

    __syncthreads();

    #pragma unroll 1
    for (int G = 0; G < NTL; ++G) {
        // ---- x tile into regs (global/L1; contiguous 160B per batch) ----
        f32x2 xt[TT][5];
        #pragma unroll
        for (int s = 0; s < TT; ++s)
            #pragma unroll
            for (int p = 0; p < 5; ++p)
                xt[s][p] = *(const f32x2*)(xb + (G * TT + s) * Hn + 2 * p);

        // ---- phase A: gx = [W_ih|Wr] . x + bias for own 15 rows ----
        #pragma unroll
        for (int cc = 0; cc < 5; ++cc) {
            #pragma unroll
            for (int j = 0; j < 3; ++j) {
                const int slot = (cc < 4 ? cc * 12 : 48) + 3 * sub + j;
                const f32x4* wp = (const f32x4*)&sWX[slot * 12];
                const f32x4 wA = wp[0], wB = wp[1], wC = wp[2];
                const int dws = (cc < 4) ? (cc * 3 + j) : (12 + j);
                #pragma unroll
                for (int s = 0; s < TT; ++s) {
                    f32x2 zz = wC.hi;            // {bias, 0}
                    zz = PKFMA(wA.lo, xt[s][0], zz);
                    zz = PKFMA(wA.hi, xt[s][1], zz);
                    zz = PKFMA(wB.lo, xt[s][2], zz);
                    zz = PKFMA(wB.hi, xt[s][3], zz);
                    zz = PKFMA(wC.lo, xt[s][4], zz);
                    sG[gbase + s * 16 + dws] = zz[0] + zz[1];
                }
            }
        }

        // ---- phase B: 4 serial steps ----
        #pragma unroll
        for (int s = 0; s < TT; ++s) {
            const int t = G * TT + s;
            const f32x2* gq = (const f32x2*)&sG[gbase + s * 16];
            const f32x2 q0 = gq[0], q1 = gq[1], q2 = gq[2], q3 = gq[3];
            const f32x2 q4 = gq[4], q5 = gq[5], q6 = gq[6], q7 = gq[7];
            // gA[g][j]: dw = g*3+j ; gR[j]: dw = 12+j
            const float gA[4][3] = {{q0[0], q0[1], q1[0]},
                                    {q1[1], q2[0], q2[1]},
                                    {q3[0], q3[1], q4[0]},
                                    {q4[1], q5[0], q5[1]}};
            const float gR[3] = {q6[0], q6[1], q7[0]};

            float z[4][3];
            #pragma unroll
            for (int g = 0; g < 4; ++g)
                #pragma unroll
                for (int j = 0; j < 3; ++j) {
                    f32x2 zz = {gA[g][j], 0.f};
                    #pragma unroll
                    for (int p = 0; p < 5; ++p) zz = PKFMA(whh[g][j][p], h2[p], zz);
                    z[g][j] = zz[0] + zz[1];
                }

            float hown[3];
            #pragma unroll
            for (int j = 0; j < 3; ++j) {
                const float si = fsigmoid(z[0][j]);
                const float sf = fsigmoid(z[1][j]);
                const float tg = ftanh(z[2][j]);
                const float so = fsigmoid(z[3][j]);
                const float cn = fmaf(sf, c[j], si * tg);
                c[j] = cn;
                hown[j] = so * ftanh(cn);
            }

            // broadcast h_{t+1}: rows 0-2<-sub0, 3-5<-sub1, 6-8<-sub2, 9<-sub3
            h2[0] = f32x2{bperm(A0, hown[0]), bperm(A0, hown[1])};
            h2[1] = f32x2{bperm(A0, hown[2]), bperm(A1, hown[0])};
            h2[2] = f32x2{bperm(A1, hown[1]), bperm(A1, hown[2])};
            h2[3] = f32x2{bperm(A2, hown[0]), bperm(A2, hown[1])};
            h2[4] = f32x2{bperm(A2, hown[2]), bperm(A3, hown[0])};

            // r-gate (own rows) + fused FC; pad rows hit zero Wfc slots
            #pragma unroll
            for (int j = 0; j < 3; ++j) {
                f32x2 zz = {gR[j], 0.f};
                #pragma unroll
                for (int p = 0; p < 5; ++p) zz = PKFMA(wnh[j][p], h2[p], zz);
                const float rg = fsigmoid(zz[0] + zz[1]);
                const float wf = sWfc[t * 12 + 3 * sub + j];
                acc = fmaf(hown[j] * rg, wf, acc);
            }
        }
    }

    // combine the 4 lanes' partial sums; sub 0 writes
    acc += __shfl_xor(acc, 1, 64);
    acc += __shfl_xor(acc, 2, 64);
    if (sub == 0) out[b] = acc;
}

extern "C" void kernel_launch(void* const* d_in, const int* in_sizes, int n_in,
                              void* d_out, int out_size, void* d_ws, size_t ws_size,
                              hipStream_t stream) {
    const float* r_emb   = (const float*)d_in[0];
    const float* feature = (const float*)d_in[1];
    const float* h0      = (const float*)d_in[2];
    const float* c0      = (const float*)d_in[3];
    const float* W_ih    = (const float*)d_in[4];
    const float* W_hh    = (const float*)d_in[5];
    const float* b_ih    = (const float*)d_in[6];
    const float* b_hh    = (const float*)d_in[7];
    const float* Wr      = (const float*)d_in[8];
    const float* br      = (const float*)d_in[9];
    const float* Wh      = (const float*)d_in[10];
    const float* bh      = (const float*)d_in[11];
    const float* Wfc     = (const float*)d_in[12];
    const float* bfc     = (const float*)d_in[13];
    float* out = (float*)d_out;

    dim3 grid(65536 / 64), block(256);
    hipLaunchKernelGGL(seqreader_kernel, grid, block, 0, stream,
                       r_emb, feature, h0, c0, W_ih, W_hh, b_ih, b_hh,
                       Wr, br, Wh, bh, Wfc, bfc, out);
}

// Round 12
// 212.899 us; speedup vs baseline: 8.4707x; 8.4707x over previous
//
#include <hip/hip_runtime.h>

#define Rn 64
#define Hn 10
#define Fn 5
#define XRS 52   // x-tile row stride in dwords (4 steps x 12, +4 pad; 16B-aligned sub-steps)

typedef float f32x2 __attribute__((ext_vector_type(2)));
typedef float f32x4 __attribute__((ext_vector_type(4)));

#define PKFMA(a, b, c) __builtin_elementwise_fma((a), (b), (c))

__device__ __forceinline__ float fsigmoid(float x) {
    return __builtin_amdgcn_rcpf(1.0f + __expf(-x));
}
__device__ __forceinline__ float ftanh(float x) {
    return 1.0f - 2.0f * __builtin_amdgcn_rcpf(__expf(2.0f * x) + 1.0f);
}

// R=2 weight-reuse: each thread runs TWO batches (bb, bb+128) through its
// 2-lane row-split role. Measured model: LDS-resident weights cost a fixed
// ~218us/R of LDS return bandwidth (broadcasts NOT deduplicated; rounds
// 4/8/10 all sit at R=1 ~ 210-245us). Every weight ds_read_b128 now feeds
// two pkFMAs -> LDS data per batch-step halves. Block = 256 threads owns
// 256 batches; grid = 256 = 1 block/CU. Weights stay in LDS (VGPR-resident
// weights spill: round 11's 1885us scratch disaster).
__global__ __launch_bounds__(256, 1) void seqreader_kernel(
    const float* __restrict__ r_emb,
    const float* __restrict__ feature,
    const float* __restrict__ h0,
    const float* __restrict__ c0,
    const float* __restrict__ W_ih,
    const float* __restrict__ W_hh,
    const float* __restrict__ b_ih,
    const float* __restrict__ b_hh,
    const float* __restrict__ Wr,
    const float* __restrict__ br,
    const float* __restrict__ Wh,
    const float* __restrict__ bh,
    const float* __restrict__ Wfc,
    const float* __restrict__ bfc,
    float* __restrict__ out)
{
    __shared__ __align__(16) float sWih[40 * 12];
    __shared__ __align__(16) float sWhh[40 * 12];
    __shared__ __align__(16) float sWr[10 * 12];
    __shared__ __align__(16) float sWhn[10 * 12];
    __shared__ float sWfc[646];
    __shared__ __align__(16) float sX[2][256 * XRS];

    const int tid  = threadIdx.x;
    const int lane = tid & 63;
    const int half = lane >> 5;        // 0: rows 0-4, 1: rows 5-9
    const int r0h  = half * 5;
    const int bb   = (tid >> 6) * 32 + (lane & 31);  // batch A within block (0..127)
    const int b0   = blockIdx.x * 256;
    const int bA   = b0 + bb;
    const int bB   = b0 + bb + 128;

    for (int i = tid; i < 400; i += 256) {
        int r = i / 10, k = i - r * 10;
        sWih[r * 12 + k] = W_ih[i];
        sWhh[r * 12 + k] = W_hh[i];
    }
    for (int i = tid; i < 100; i += 256) {
        int r = i / 10, k = i - r * 10;
        sWr[r * 12 + k]  = Wr[i];
        sWhn[r * 12 + k] = Wh[i];
    }
    for (int i = tid; i < 645; i += 256) sWfc[i] = Wfc[i];

    float bi[5], bf_[5], bg_[5], bo[5], brh[5];
#pragma unroll
    for (int j = 0; j < 5; ++j) {
        bi[j]  = b_ih[0  + r0h + j] + b_hh[0  + r0h + j];
        bf_[j] = b_ih[10 + r0h + j] + b_hh[10 + r0h + j];
        bg_[j] = b_ih[20 + r0h + j] + b_hh[20 + r0h + j];
        bo[j]  = b_ih[30 + r0h + j] + b_hh[30 + r0h + j];
        brh[j] = br[r0h + j] + bh[r0h + j];
    }

    float cA[5], cB[5];
#pragma unroll
    for (int j = 0; j < 5; ++j) {
        cA[j] = c0[(size_t)bA * Hn + r0h + j];
        cB[j] = c0[(size_t)bB * Hn + r0h + j];
    }
    float hfA[Hn], hfB[Hn];
#pragma unroll
    for (int k = 0; k < Hn; ++k) {
        hfA[k] = h0[(size_t)bA * Hn + k];
        hfB[k] = h0[(size_t)bB * Hn + k];
    }

    float accA = 0.0f, accB = 0.0f;
    if (half == 0) {
        accA = bfc[0];
        accB = bfc[0];
#pragma unroll
        for (int k = 0; k < Fn; ++k) {
            accA = fmaf(feature[(size_t)bA * Fn + k], Wfc[Rn * Hn + k], accA);
            accB = fmaf(feature[(size_t)bB * Fn + k], Wfc[Rn * Hn + k], accB);
        }
    }

    // gather map: tile = 256 batches x 40 floats = 2560 float4; 10 per thread
    unsigned off_g[10], off_l[10][4];
#pragma unroll
    for (int k = 0; k < 10; ++k) {
        int q  = k * 256 + tid;
        int bq = q / 10;
        int e  = q - bq * 10;
        off_g[k] = (unsigned)((bq * (Rn * Hn) + e * 4) * 4);  // bytes
#pragma unroll
        for (int cidx = 0; cidx < 4; ++cidx) {
            int u = e * 4 + cidx;            // element 0..39 within batch-tile
            int s = u / 10, kk = u - s * 10; // step-in-tile, k
            off_l[k][cidx] = (unsigned)(bq * XRS + s * 12 + kk);
        }
    }
    const char* gb = (const char*)(r_emb + (size_t)b0 * (Rn * Hn));

    // stage tile 0
    {
        float4 s0[10];
#pragma unroll
        for (int k = 0; k < 10; ++k) s0[k] = *(const float4*)(gb + off_g[k]);
#pragma unroll
        for (int k = 0; k < 10; ++k) {
            sX[0][off_l[k][0]] = s0[k].x;
            sX[0][off_l[k][1]] = s0[k].y;
            sX[0][off_l[k][2]] = s0[k].z;
            sX[0][off_l[k][3]] = s0[k].w;
        }
    }
    __syncthreads();

    float4 st[10];
#pragma unroll 1
    for (int t = 0; t < Rn; ++t) {
        const int tt = t & 3;
        const int Tb = (t >> 2) & 1;

        if (tt == 0 && t + 4 < Rn) {
#pragma unroll
            for (int k = 0; k < 10; ++k)
                st[k] = *(const float4*)(gb + off_g[k] + (unsigned)(t / 4 + 1) * 160u);
        }

        // x_t for both batches: 3x b128 each
        const f32x4* xrA = (const f32x4*)&sX[Tb][bb * XRS + tt * 12];
        const f32x4* xrB = (const f32x4*)&sX[Tb][(bb + 128) * XRS + tt * 12];
        const f32x4 xa0 = xrA[0], xa1 = xrA[1], xa2 = xrA[2];
        const f32x4 xb0 = xrB[0], xb1 = xrB[1], xb2 = xrB[2];

        f32x2 hA[5], hB[5];
#pragma unroll
        for (int p = 0; p < 5; ++p) {
            hA[p] = f32x2{hfA[2 * p], hfA[2 * p + 1]};
            hB[p] = f32x2{hfB[2 * p], hfB[2 * p + 1]};
        }

        // own half of the LSTM cell; each weight load feeds both batches
        float hnA[5], hnB[5];
#pragma unroll
        for (int j = 0; j < 5; ++j) {
            float zgA[4], zgB[4];
#pragma unroll
            for (int gidx = 0; gidx < 4; ++gidx) {
                const int row = gidx * 10 + r0h + j;
                const f32x4* wi = (const f32x4*)&sWih[row * 12];
                const f32x4* wh = (const f32x4*)&sWhh[row * 12];
                const f32x4 wi0 = wi[0], wi1 = wi[1], wi2 = wi[2];
                const f32x4 wh0 = wh[0], wh1 = wh[1], wh2 = wh[2];
                f32x2 zA = {0.f, 0.f}, zB = {0.f, 0.f};
                zA = PKFMA(wi0.lo, xa0.lo, zA);  zB = PKFMA(wi0.lo, xb0.lo, zB);
                zA = PKFMA(wi0.hi, xa0.hi, zA);  zB = PKFMA(wi0.hi, xb0.hi, zB);
                zA = PKFMA(wi1.lo, xa1.lo, zA);  zB = PKFMA(wi1.lo, xb1.lo, zB);
                zA = PKFMA(wi1.hi, xa1.hi, zA);  zB = PKFMA(wi1.hi, xb1.hi, zB);
                zA = PKFMA(wi2.lo, xa2.lo, zA);  zB = PKFMA(wi2.lo, xb2.lo, zB);
                zA = PKFMA(wh0.lo, hA[0], zA);   zB = PKFMA(wh0.lo, hB[0], zB);
                zA = PKFMA(wh0.hi, hA[1], zA);   zB = PKFMA(wh0.hi, hB[1], zB);
                zA = PKFMA(wh1.lo, hA[2], zA);   zB = PKFMA(wh1.lo, hB[2], zB);
                zA = PKFMA(wh1.hi, hA[3], zA);   zB = PKFMA(wh1.hi, hB[3], zB);
                zA = PKFMA(wh2.lo, hA[4], zA);   zB = PKFMA(wh2.lo, hB[4], zB);
                zgA[gidx] = zA[0] + zA[1];
                zgB[gidx] = zB[0] + zB[1];
            }
            {
                const float si = fsigmoid(zgA[0] + bi[j]);
                const float sf = fsigmoid(zgA[1] + bf_[j]);
                const float tg = ftanh(zgA[2] + bg_[j]);
                const float so = fsigmoid(zgA[3] + bo[j]);
                const float cn = fmaf(sf, cA[j], si * tg);
                cA[j] = cn;
                hnA[j] = so * ftanh(cn);
            }
            {
                const float si = fsigmoid(zgB[0] + bi[j]);
                const float sf = fsigmoid(zgB[1] + bf_[j]);
                const float tg = ftanh(zgB[2] + bg_[j]);
                const float so = fsigmoid(zgB[3] + bo[j]);
                const float cn = fmaf(sf, cB[j], si * tg);
                cB[j] = cn;
                hnB[j] = so * ftanh(cn);
            }
        }

        // exchange halves in-wave: partner lane = lane ^ 32
#pragma unroll
        for (int j = 0; j < 5; ++j) {
            const float swA = __shfl_xor(hnA[j], 32, 64);
            const float swB = __shfl_xor(hnB[j], 32, 64);
            hfA[j]     = half ? swA : hnA[j];
            hfA[5 + j] = half ? hnA[j] : swA;
            hfB[j]     = half ? swB : hnB[j];
            hfB[5 + j] = half ? hnB[j] : swB;
        }

        // write next x tile into the other buffer (prefetched at tt==0)
        if (tt == 2 && t + 2 < Rn) {
#pragma unroll
            for (int k = 0; k < 10; ++k) {
                sX[Tb ^ 1][off_l[k][0]] = st[k].x;
                sX[Tb ^ 1][off_l[k][1]] = st[k].y;
                sX[Tb ^ 1][off_l[k][2]] = st[k].z;
                sX[Tb ^ 1][off_l[k][3]] = st[k].w;
            }
        }

        // r-gate + fused FC accumulation (own rows); weight loads shared
        f32x2 hnA2[5], hnB2[5];
#pragma unroll
        for (int p = 0; p < 5; ++p) {
            hnA2[p] = f32x2{hfA[2 * p], hfA[2 * p + 1]};
            hnB2[p] = f32x2{hfB[2 * p], hfB[2 * p + 1]};
        }
#pragma unroll
        for (int j = 0; j < 5; ++j) {
            const int row = r0h + j;
            const f32x4* wr_ = (const f32x4*)&sWr[row * 12];
            const f32x4* wh_ = (const f32x4*)&sWhn[row * 12];
            const f32x4 wr0 = wr_[0], wr1 = wr_[1], wr2 = wr_[2];
            const f32x4 wh0 = wh_[0], wh1 = wh_[1], wh2 = wh_[2];
            f32x2 zA = {0.f, 0.f}, zB = {0.f, 0.f};
            zA = PKFMA(wr0.lo, xa0.lo, zA);  zB = PKFMA(wr0.lo, xb0.lo, zB);
            zA = PKFMA(wr0.hi, xa0.hi, zA);  zB = PKFMA(wr0.hi, xb0.hi, zB);
            zA = PKFMA(wr1.lo, xa1.lo, zA);  zB = PKFMA(wr1.lo, xb1.lo, zB);
            zA = PKFMA(wr1.hi, xa1.hi, zA);  zB = PKFMA(wr1.hi, xb1.hi, zB);
            zA = PKFMA(wr2.lo, xa2.lo, zA);  zB = PKFMA(wr2.lo, xb2.lo, zB);
            zA = PKFMA(wh0.lo, hnA2[0], zA); zB = PKFMA(wh0.lo, hnB2[0], zB);
            zA = PKFMA(wh0.hi, hnA2[1], zA); zB = PKFMA(wh0.hi, hnB2[1], zB);
            zA = PKFMA(wh1.lo, hnA2[2], zA); zB = PKFMA(wh1.lo, hnB2[2], zB);
            zA = PKFMA(wh1.hi, hnA2[3], zA); zB = PKFMA(wh1.hi, hnB2[3], zB);
            zA = PKFMA(wh2.lo, hnA2[4], zA); zB = PKFMA(wh2.lo, hnB2[4], zB);
            const float sA = zA[0] + zA[1] + brh[j];
            const float sB = zB[0] + zB[1] + brh[j];
            const float wf = sWfc[t * Hn + r0h + j];
            accA = fmaf(hnA[j] * fsigmoid(sA), wf, accA);
            accB = fmaf(hnB[j] * fsigmoid(sB), wf, accB);
        }

        if (tt == 3) __syncthreads();
    }

    // combine the two lane-halves' partial FC sums; half 0 writes both batches
    accA += __shfl_xor(accA, 32, 64);
    accB += __shfl_xor(accB, 32, 64);
    if (half == 0) {
        out[bA] = accA;
        out[bB] = accB;
    }
}

extern "C" void kernel_launch(void* const* d_in, const int* in_sizes, int n_in,
                              void* d_out, int out_size, void* d_ws, size_t ws_size,
                              hipStream_t stream) {
    const float* r_emb   = (const float*)d_in[0];
    const float* feature = (const float*)d_in[1];
    const float* h0      = (const float*)d_in[2];
    const float* c0      = (const float*)d_in[3];
    const float* W_ih    = (const float*)d_in[4];
    const float* W_hh    = (const float*)d_in[5];
    const float* b_ih    = (const float*)d_in[6];
    const float* b_hh    = (const float*)d_in[7];
    const float* Wr      = (const float*)d_in[8];
    const float* br      = (const float*)d_in[9];
    const float* Wh      = (const float*)d_in[10];
    const float* bh      = (const float*)d_in[11];
    const float* Wfc     = (const float*)d_in[12];
    const float* bfc     = (const float*)d_in[13];
    float* out = (float*)d_out;

    dim3 grid(65536 / 256), block(256);
    hipLaunchKernelGGL(seqreader_kernel, grid, block, 0, stream,
                       r_emb, feature, h0, c0, W_ih, W_hh, b_ih, b_hh,
                       Wr, br, Wh, bh, Wfc, bfc, out);
}